// Round 1
// baseline (2389.892 us; speedup 1.0000x reference)
//
#include <hip/hip_runtime.h>
#include <hip/hip_bf16.h>

#define N_EMBD 1024
#define N_HEADS 16
#define HD 64
#define TSEQ 2048
#define BATCH 4
#define M_TOT (BATCH*TSEQ)   // 8192

typedef short s16x8 __attribute__((ext_vector_type(8)));
typedef float f32x4 __attribute__((ext_vector_type(4)));

__device__ __forceinline__ float bf16lo(unsigned u) { return __uint_as_float(u << 16); }
__device__ __forceinline__ float bf16hi(unsigned u) { return __uint_as_float(u & 0xffff0000u); }

// ---- cast x fp32 -> bf16, 4 elems/thread ----
__global__ __launch_bounds__(256) void xcast_kernel(const float* __restrict__ x,
                                                    __hip_bfloat16* __restrict__ xb) {
  int i = blockIdx.x * 256 + threadIdx.x;
  float4 f = ((const float4*)x)[i];
  __hip_bfloat162 p0, p1;
  p0.x = __float2bfloat16(f.x); p0.y = __float2bfloat16(f.y);
  p1.x = __float2bfloat16(f.z); p1.y = __float2bfloat16(f.w);
  ((__hip_bfloat162*)xb)[2*i]   = p0;
  ((__hip_bfloat162*)xb)[2*i+1] = p1;
}

// ---- transpose + cast weights: out[n][c] = in[c][n], bf16 ----
__global__ void wcast_kernel(const float* __restrict__ Wq, const float* __restrict__ Wk,
                             const float* __restrict__ Wv, const float* __restrict__ Wp,
                             __hip_bfloat16* __restrict__ wqkvt, __hip_bfloat16* __restrict__ wpt) {
  __shared__ float tile[32][33];
  int z = blockIdx.z;
  const float* in = (z==0)?Wq:(z==1)?Wk:(z==2)?Wv:Wp;
  __hip_bfloat16* out = (z<3) ? (wqkvt + (size_t)z*N_EMBD*N_EMBD) : wpt;
  int tx = threadIdx.x, ty = threadIdx.y;
  int x  = blockIdx.x*32 + tx;
  int y0 = blockIdx.y*32;
  #pragma unroll
  for (int j=0;j<4;++j) tile[ty + j*8][tx] = in[(size_t)(y0+ty+j*8)*N_EMBD + x];
  __syncthreads();
  int xo  = y0 + tx;
  int yo0 = blockIdx.x*32;
  #pragma unroll
  for (int j=0;j<4;++j)
    out[(size_t)(yo0+ty+j*8)*N_EMBD + xo] = __float2bfloat16(tile[tx][ty+j*8]);
}

// ---- bf16 MFMA GEMM: C[m][n] = sum_k A[m][k] * Bt[n][k]
// mode 0: N=3072 (QKV), scatter into Q/K/V [B,H,T,d] bf16
// mode 1: N=1024 (proj), out fp32 = acc + bias
__global__ __launch_bounds__(256) void gemm_kernel(
    const __hip_bfloat16* __restrict__ A,   // [M][1024] bf16
    const __hip_bfloat16* __restrict__ Bt,  // [N][1024] bf16 (transposed weight)
    __hip_bfloat16* __restrict__ Qb, __hip_bfloat16* __restrict__ Kb,
    __hip_bfloat16* __restrict__ Vb,
    float* __restrict__ out, const float* __restrict__ bias, int mode) {
  __shared__ __align__(16) __hip_bfloat16 As[64][40];  // +8 pad keeps 16B align, breaks pow2 stride
  __shared__ __align__(16) __hip_bfloat16 Bs[64][40];
  int tid = threadIdx.x;
  int m0 = blockIdx.y*64, n0 = blockIdx.x*64;
  int ar = tid>>2, ac8 = (tid&3)*8;          // staging: row 0..63, 8-elem chunk
  int w = tid>>6, lane = tid&63, l16 = lane&15, quad = lane>>4;
  int wm = (w>>1)*32, wn = (w&1)*32;
  f32x4 z4 = {0.f,0.f,0.f,0.f};
  f32x4 acc00=z4, acc01=z4, acc10=z4, acc11=z4;

  for (int k0=0; k0<N_EMBD; k0+=32) {
    uint4 av = *(const uint4*)(A  + (size_t)(m0+ar)*N_EMBD + k0 + ac8);
    uint4 bv = *(const uint4*)(Bt + (size_t)(n0+ar)*N_EMBD + k0 + ac8);
    *(uint4*)&As[ar][ac8] = av;
    *(uint4*)&Bs[ar][ac8] = bv;
    __syncthreads();
    s16x8 a0 = *(const s16x8*)&As[wm+l16][quad*8];
    s16x8 a1 = *(const s16x8*)&As[wm+16+l16][quad*8];
    s16x8 b0 = *(const s16x8*)&Bs[wn+l16][quad*8];
    s16x8 b1 = *(const s16x8*)&Bs[wn+16+l16][quad*8];
    acc00 = __builtin_amdgcn_mfma_f32_16x16x32_bf16(a0,b0,acc00,0,0,0);
    acc01 = __builtin_amdgcn_mfma_f32_16x16x32_bf16(a0,b1,acc01,0,0,0);
    acc10 = __builtin_amdgcn_mfma_f32_16x16x32_bf16(a1,b0,acc10,0,0,0);
    acc11 = __builtin_amdgcn_mfma_f32_16x16x32_bf16(a1,b1,acc11,0,0,0);
    __syncthreads();
  }

  if (mode == 0) {
    int which = n0 >> 10;
    int hh = (n0 & 1023) >> 6;                 // n0 is 64-aligned -> single head per block
    __hip_bfloat16* outp = (which==0)?Qb:((which==1)?Kb:Vb);
    #pragma unroll
    for (int mi=0;mi<2;++mi) {
      #pragma unroll
      for (int ni=0;ni<2;++ni) {
        f32x4 a = (mi==0)?((ni==0)?acc00:acc01):((ni==0)?acc10:acc11);
        int col = wn + ni*16 + l16;            // = d within head
        #pragma unroll
        for (int r=0;r<4;++r) {
          int m = m0 + wm + mi*16 + quad*4 + r;
          int bb = m >> 11, t = m & 2047;
          outp[((size_t)(bb*N_HEADS + hh)*TSEQ + t)*HD + col] = __float2bfloat16(a[r]);
        }
      }
    }
  } else {
    #pragma unroll
    for (int mi=0;mi<2;++mi) {
      #pragma unroll
      for (int ni=0;ni<2;++ni) {
        f32x4 a = (mi==0)?((ni==0)?acc00:acc01):((ni==0)?acc10:acc11);
        int col = n0 + wn + ni*16 + l16;
        float bs = bias[col];
        #pragma unroll
        for (int r=0;r<4;++r) {
          int m = m0 + wm + mi*16 + quad*4 + r;
          out[(size_t)m*N_EMBD + col] = a[r] + bs;
        }
      }
    }
  }
}

// ---- causal flash attention, one thread per query row ----
// K/V tiles (32 keys x 64d) staged to LDS as fp32; no max-subtraction needed
// (scores sigma~1 after 1/8 scale; exp cannot overflow fp32; /l normalizes).
__global__ __launch_bounds__(256) void attn_kernel(
    const __hip_bfloat16* __restrict__ Qb, const __hip_bfloat16* __restrict__ Kb,
    const __hip_bfloat16* __restrict__ Vb, __hip_bfloat16* __restrict__ Yb) {
  __shared__ __align__(16) float Ks[32][64];
  __shared__ __align__(16) float Vs[32][64];
  int tid = threadIdx.x;
  int qt = blockIdx.x, h = blockIdx.y, b = blockIdx.z;
  int qi = qt*256 + tid;
  size_t bh = (size_t)(b*N_HEADS + h)*TSEQ;

  float q[64];
  {
    const uint4* qrow = (const uint4*)(Qb + (bh + qi)*HD);
    #pragma unroll
    for (int c=0;c<8;++c) {
      uint4 u = qrow[c];
      q[c*8+0]=bf16lo(u.x); q[c*8+1]=bf16hi(u.x);
      q[c*8+2]=bf16lo(u.y); q[c*8+3]=bf16hi(u.y);
      q[c*8+4]=bf16lo(u.z); q[c*8+5]=bf16hi(u.z);
      q[c*8+6]=bf16lo(u.w); q[c*8+7]=bf16hi(u.w);
    }
  }
  float o[64];
  #pragma unroll
  for (int c=0;c<64;++c) o[c]=0.f;
  float l = 0.f;

  int key = tid>>3, c8 = (tid&7)*8;            // staging: one 16B chunk of K and V each
  int ntiles = (qt+1)*8;
  for (int t=0;t<ntiles;++t) {
    int k0 = t*32;
    __syncthreads();
    {
      uint4 ku = *(const uint4*)(Kb + (bh + k0 + key)*HD + c8);
      uint4 vu = *(const uint4*)(Vb + (bh + k0 + key)*HD + c8);
      float4 f0, f1;
      f0.x=bf16lo(ku.x); f0.y=bf16hi(ku.x); f0.z=bf16lo(ku.y); f0.w=bf16hi(ku.y);
      f1.x=bf16lo(ku.z); f1.y=bf16hi(ku.z); f1.z=bf16lo(ku.w); f1.w=bf16hi(ku.w);
      *(float4*)&Ks[key][c8]   = f0;
      *(float4*)&Ks[key][c8+4] = f1;
      f0.x=bf16lo(vu.x); f0.y=bf16hi(vu.x); f0.z=bf16lo(vu.y); f0.w=bf16hi(vu.y);
      f1.x=bf16lo(vu.z); f1.y=bf16hi(vu.z); f1.z=bf16lo(vu.w); f1.w=bf16hi(vu.w);
      *(float4*)&Vs[key][c8]   = f0;
      *(float4*)&Vs[key][c8+4] = f1;
    }
    __syncthreads();
    if (qi >= k0) {
      int jmax = min(31, qi - k0);
      for (int j=0;j<=jmax;++j) {
        const float4* kr = (const float4*)Ks[j];   // wave-uniform addr -> LDS broadcast
        float s0=0.f,s1=0.f,s2=0.f,s3=0.f;
        #pragma unroll
        for (int c=0;c<16;++c) {
          float4 kf = kr[c];
          s0 = fmaf(q[4*c+0], kf.x, s0);
          s1 = fmaf(q[4*c+1], kf.y, s1);
          s2 = fmaf(q[4*c+2], kf.z, s2);
          s3 = fmaf(q[4*c+3], kf.w, s3);
        }
        float p = __expf(((s0+s1)+(s2+s3))*0.125f);
        l += p;
        const float4* vr = (const float4*)Vs[j];
        #pragma unroll
        for (int c=0;c<16;++c) {
          float4 vf = vr[c];
          o[4*c+0] = fmaf(p, vf.x, o[4*c+0]);
          o[4*c+1] = fmaf(p, vf.y, o[4*c+1]);
          o[4*c+2] = fmaf(p, vf.z, o[4*c+2]);
          o[4*c+3] = fmaf(p, vf.w, o[4*c+3]);
        }
      }
    }
  }
  float inv = 1.f / l;
  __hip_bfloat16* yr = Yb + ((size_t)(b*TSEQ + qi))*N_EMBD + h*HD;
  #pragma unroll
  for (int c=0;c<64;c+=2) {
    __hip_bfloat162 pp;
    pp.x = __float2bfloat16(o[c]*inv);
    pp.y = __float2bfloat16(o[c+1]*inv);
    *(__hip_bfloat162*)(yr + c) = pp;
  }
}

extern "C" void kernel_launch(void* const* d_in, const int* in_sizes, int n_in,
                              void* d_out, int out_size, void* d_ws, size_t ws_size,
                              hipStream_t stream) {
  const float* x  = (const float*)d_in[0];
  const float* Wq = (const float*)d_in[1];
  const float* Wk = (const float*)d_in[2];
  const float* Wv = (const float*)d_in[3];
  const float* Wp = (const float*)d_in[4];
  const float* bp = (const float*)d_in[5];

  char* w = (char*)d_ws;
  __hip_bfloat16* xb    = (__hip_bfloat16*)w;  w += (size_t)M_TOT*N_EMBD*2;   // 16 MB
  __hip_bfloat16* wqkvt = (__hip_bfloat16*)w;  w += (size_t)3*N_EMBD*N_EMBD*2;// 6 MB
  __hip_bfloat16* wpt   = (__hip_bfloat16*)w;  w += (size_t)N_EMBD*N_EMBD*2;  // 2 MB
  __hip_bfloat16* Qb    = (__hip_bfloat16*)w;  w += (size_t)M_TOT*N_EMBD*2;   // 16 MB
  __hip_bfloat16* Kb    = (__hip_bfloat16*)w;  w += (size_t)M_TOT*N_EMBD*2;   // 16 MB
  __hip_bfloat16* Vb    = (__hip_bfloat16*)w;  w += (size_t)M_TOT*N_EMBD*2;   // 16 MB
  __hip_bfloat16* Yb    = (__hip_bfloat16*)w;                                  // 16 MB (88 MB total)

  xcast_kernel<<<dim3(M_TOT*N_EMBD/1024), dim3(256), 0, stream>>>(x, xb);
  wcast_kernel<<<dim3(32,32,4), dim3(32,8), 0, stream>>>(Wq,Wk,Wv,Wp,wqkvt,wpt);
  gemm_kernel<<<dim3(48,128), dim3(256), 0, stream>>>(xb, wqkvt, Qb,Kb,Vb, nullptr, nullptr, 0);
  attn_kernel<<<dim3(8,N_HEADS,BATCH), dim3(256), 0, stream>>>(Qb,Kb,Vb,Yb);
  gemm_kernel<<<dim3(16,128), dim3(256), 0, stream>>>(Yb, wpt, nullptr,nullptr,nullptr,
                                                      (float*)d_out, bp, 1);
}

// Round 2
// 387.772 us; speedup vs baseline: 6.1631x; 6.1631x over previous
//
#include <hip/hip_runtime.h>
#include <hip/hip_bf16.h>

#define N_EMBD 1024
#define N_HEADS 16
#define HD 64
#define TSEQ 2048
#define BATCH 4
#define M_TOT (BATCH*TSEQ)   // 8192

typedef short s16x8 __attribute__((ext_vector_type(8)));
typedef float f32x4 __attribute__((ext_vector_type(4)));

// ---- cast x fp32 -> bf16, 4 elems/thread ----
__global__ __launch_bounds__(256) void xcast_kernel(const float* __restrict__ x,
                                                    __hip_bfloat16* __restrict__ xb) {
  int i = blockIdx.x * 256 + threadIdx.x;
  float4 f = ((const float4*)x)[i];
  __hip_bfloat162 p0, p1;
  p0.x = __float2bfloat16(f.x); p0.y = __float2bfloat16(f.y);
  p1.x = __float2bfloat16(f.z); p1.y = __float2bfloat16(f.w);
  ((__hip_bfloat162*)xb)[2*i]   = p0;
  ((__hip_bfloat162*)xb)[2*i+1] = p1;
}

// ---- transpose + cast weights: out[n][c] = in[c][n], bf16 ----
__global__ void wcast_kernel(const float* __restrict__ Wq, const float* __restrict__ Wk,
                             const float* __restrict__ Wv, const float* __restrict__ Wp,
                             __hip_bfloat16* __restrict__ wqkvt, __hip_bfloat16* __restrict__ wpt) {
  __shared__ float tile[32][33];
  int z = blockIdx.z;
  const float* in = (z==0)?Wq:(z==1)?Wk:(z==2)?Wv:Wp;
  __hip_bfloat16* out = (z<3) ? (wqkvt + (size_t)z*N_EMBD*N_EMBD) : wpt;
  int tx = threadIdx.x, ty = threadIdx.y;
  int x  = blockIdx.x*32 + tx;
  int y0 = blockIdx.y*32;
  #pragma unroll
  for (int j=0;j<4;++j) tile[ty + j*8][tx] = in[(size_t)(y0+ty+j*8)*N_EMBD + x];
  __syncthreads();
  int xo  = y0 + tx;
  int yo0 = blockIdx.x*32;
  #pragma unroll
  for (int j=0;j<4;++j)
    out[(size_t)(yo0+ty+j*8)*N_EMBD + xo] = __float2bfloat16(tile[tx][ty+j*8]);
}

// ---- bf16 MFMA GEMM: C[m][n] = sum_k A[m][k] * Bt[n][k]
// mode 0: N=3072 (QKV). Q,K scatter into [B,H,T,d] bf16; V stores TRANSPOSED
//         [B,H,d,T] (LDS tile transpose, coalesced along T).
// mode 1: N=1024 (proj), out fp32 = acc + bias
__global__ __launch_bounds__(256) void gemm_kernel(
    const __hip_bfloat16* __restrict__ A,   // [M][1024] bf16
    const __hip_bfloat16* __restrict__ Bt,  // [N][1024] bf16 (transposed weight)
    __hip_bfloat16* __restrict__ Qb, __hip_bfloat16* __restrict__ Kb,
    __hip_bfloat16* __restrict__ Vt,        // [B,H,d,T]
    float* __restrict__ out, const float* __restrict__ bias, int mode) {
  __shared__ __align__(16) char smem[10240];
  __hip_bfloat16 (*As)[40] = (__hip_bfloat16(*)[40])smem;          // 64x40
  __hip_bfloat16 (*Bs)[40] = (__hip_bfloat16(*)[40])(smem + 5120); // 64x40
  int tid = threadIdx.x;
  int m0 = blockIdx.y*64, n0 = blockIdx.x*64;
  int ar = tid>>2, ac8 = (tid&3)*8;          // staging: row 0..63, 8-elem chunk
  int w = tid>>6, lane = tid&63, l16 = lane&15, quad = lane>>4;
  int wm = (w>>1)*32, wn = (w&1)*32;
  f32x4 z4 = {0.f,0.f,0.f,0.f};
  f32x4 acc00=z4, acc01=z4, acc10=z4, acc11=z4;

  for (int k0=0; k0<N_EMBD; k0+=32) {
    uint4 av = *(const uint4*)(A  + (size_t)(m0+ar)*N_EMBD + k0 + ac8);
    uint4 bv = *(const uint4*)(Bt + (size_t)(n0+ar)*N_EMBD + k0 + ac8);
    *(uint4*)&As[ar][ac8] = av;
    *(uint4*)&Bs[ar][ac8] = bv;
    __syncthreads();
    s16x8 a0 = *(const s16x8*)&As[wm+l16][quad*8];
    s16x8 a1 = *(const s16x8*)&As[wm+16+l16][quad*8];
    s16x8 b0 = *(const s16x8*)&Bs[wn+l16][quad*8];
    s16x8 b1 = *(const s16x8*)&Bs[wn+16+l16][quad*8];
    acc00 = __builtin_amdgcn_mfma_f32_16x16x32_bf16(a0,b0,acc00,0,0,0);
    acc01 = __builtin_amdgcn_mfma_f32_16x16x32_bf16(a0,b1,acc01,0,0,0);
    acc10 = __builtin_amdgcn_mfma_f32_16x16x32_bf16(a1,b0,acc10,0,0,0);
    acc11 = __builtin_amdgcn_mfma_f32_16x16x32_bf16(a1,b1,acc11,0,0,0);
    __syncthreads();
  }

  if (mode == 0) {
    int which = n0 >> 10;
    int hh = (n0 & 1023) >> 6;                 // n0 is 64-aligned -> single head per block
    int bb = m0 >> 11, t0 = m0 & 2047;
    if (which < 2) {
      __hip_bfloat16* outp = (which==0)?Qb:Kb;
      #pragma unroll
      for (int mi=0;mi<2;++mi) {
        #pragma unroll
        for (int ni=0;ni<2;++ni) {
          f32x4 a = (mi==0)?((ni==0)?acc00:acc01):((ni==0)?acc10:acc11);
          int col = wn + ni*16 + l16;            // = d within head
          #pragma unroll
          for (int r=0;r<4;++r) {
            int t = t0 + wm + mi*16 + quad*4 + r;
            outp[((size_t)(bb*N_HEADS + hh)*TSEQ + t)*HD + col] = __float2bfloat16(a[r]);
          }
        }
      }
    } else {
      // V: transpose 64x64 tile in LDS, store [B,H,d,T] coalesced along T
      __syncthreads();
      __hip_bfloat16 (*Ts)[72] = (__hip_bfloat16(*)[72])smem;   // 64x72x2 = 9216 <= 10240
      #pragma unroll
      for (int mi=0;mi<2;++mi) {
        #pragma unroll
        for (int ni=0;ni<2;++ni) {
          f32x4 a = (mi==0)?((ni==0)?acc00:acc01):((ni==0)?acc10:acc11);
          int col = wn + ni*16 + l16;            // d
          #pragma unroll
          for (int r=0;r<4;++r)
            Ts[col][wm + mi*16 + quad*4 + r] = __float2bfloat16(a[r]);
        }
      }
      __syncthreads();
      int d = tid>>2, tc = (tid&3)*16;
      __hip_bfloat16* dst = Vt + ((size_t)(bb*N_HEADS + hh)*HD + d)*TSEQ + t0 + tc;
      *(uint4*)dst     = *(const uint4*)&Ts[d][tc];
      *(uint4*)(dst+8) = *(const uint4*)&Ts[d][tc+8];
    }
  } else {
    #pragma unroll
    for (int mi=0;mi<2;++mi) {
      #pragma unroll
      for (int ni=0;ni<2;++ni) {
        f32x4 a = (mi==0)?((ni==0)?acc00:acc01):((ni==0)?acc10:acc11);
        int col = n0 + wn + ni*16 + l16;
        float bs = bias[col];
        #pragma unroll
        for (int r=0;r<4;++r) {
          int m = m0 + wm + mi*16 + quad*4 + r;
          out[(size_t)m*N_EMBD + col] = a[r] + bs;
        }
      }
    }
  }
}

// ---- MFMA causal flash attention ----
// Block: 64 queries x (head,batch). 4 waves; wave w owns query rows wm..wm+15.
// Per 64-key tile: S=QK^T (MFMA), mask+exp (no max-subtraction: sigma(s)~1,
// exp can't overflow fp32; /l at the end), P->LDS (C->A layout), O+=P*V (MFMA).
// V arrives TRANSPOSED [B,H,d,T] so PV B-frags read contiguous.
#define AST 72   // LDS row stride (bf16): 16B-aligned rows, frag reads 2-way(free)
__global__ __launch_bounds__(256) void attn_kernel(
    const __hip_bfloat16* __restrict__ Qb, const __hip_bfloat16* __restrict__ Kb,
    const __hip_bfloat16* __restrict__ Vt, __hip_bfloat16* __restrict__ Yb) {
  __shared__ __align__(16) __hip_bfloat16 Ks[64][AST];   // [key][d]
  __shared__ __align__(16) __hip_bfloat16 Vs[64][AST];   // [d][key]
  __shared__ __align__(16) __hip_bfloat16 Ps[64][AST];   // [q][key]
  int tid = threadIdx.x;
  int qb = blockIdx.x, h = blockIdx.y, b = blockIdx.z;
  int q0 = qb*64;
  size_t bhT = (size_t)(b*N_HEADS + h)*TSEQ;
  int lane = tid&63, w = tid>>6, l16 = lane&15, quad = lane>>4;
  int wm = w*16;

  // Q fragments in registers (A-layout), once per block
  s16x8 qf0 = *(const s16x8*)(Qb + (bhT + q0 + wm + l16)*HD + quad*8);
  s16x8 qf1 = *(const s16x8*)(Qb + (bhT + q0 + wm + l16)*HD + 32 + quad*8);

  f32x4 z4 = {0.f,0.f,0.f,0.f};
  f32x4 oacc[4] = {z4,z4,z4,z4};
  float lrow[4] = {0.f,0.f,0.f,0.f};

  int sr = tid>>2, sc = (tid&3)*16;   // staging coords
  const __hip_bfloat16* vbase = Vt + (((size_t)(b*N_HEADS + h))*HD + sr)*TSEQ;

  int ntiles = qb + 1;
  for (int t=0; t<ntiles; ++t) {
    int k0 = t*64;
    __syncthreads();   // prev tile's frag reads done before restaging
    {
      const uint4* ksrc = (const uint4*)(Kb + (bhT + k0 + sr)*HD + sc);
      *(uint4*)&Ks[sr][sc]   = ksrc[0];
      *(uint4*)&Ks[sr][sc+8] = ksrc[1];
      const uint4* vsrc = (const uint4*)(vbase + k0 + sc);
      *(uint4*)&Vs[sr][sc]   = vsrc[0];
      *(uint4*)&Vs[sr][sc+8] = vsrc[1];
    }
    __syncthreads();

    // S = Q K^T : 16q x 64key per wave
    f32x4 sacc[4] = {z4,z4,z4,z4};
    #pragma unroll
    for (int ni=0; ni<4; ++ni) {
      s16x8 b0 = *(const s16x8*)&Ks[ni*16+l16][quad*8];
      s16x8 b1 = *(const s16x8*)&Ks[ni*16+l16][32+quad*8];
      sacc[ni] = __builtin_amdgcn_mfma_f32_16x16x32_bf16(qf0, b0, sacc[ni],0,0,0);
      sacc[ni] = __builtin_amdgcn_mfma_f32_16x16x32_bf16(qf1, b1, sacc[ni],0,0,0);
    }

    // mask + exp; accumulate l; P -> LDS (own 16-row band, no barrier needed:
    // same-wave LDS write->read ordering is handled by lgkmcnt)
    int qrb = q0 + wm + quad*4;
    #pragma unroll
    for (int ni=0; ni<4; ++ni) {
      int kcol = k0 + ni*16 + l16;
      #pragma unroll
      for (int r=0; r<4; ++r) {
        float p = (qrb + r >= kcol) ? __expf(sacc[ni][r]*0.125f) : 0.f;
        lrow[r] += p;
        Ps[wm + quad*4 + r][ni*16 + l16] = __float2bfloat16(p);
      }
    }

    // O += P V
    s16x8 a0 = *(const s16x8*)&Ps[wm+l16][quad*8];
    s16x8 a1 = *(const s16x8*)&Ps[wm+l16][32+quad*8];
    #pragma unroll
    for (int ni=0; ni<4; ++ni) {
      s16x8 b0 = *(const s16x8*)&Vs[ni*16+l16][quad*8];
      s16x8 b1 = *(const s16x8*)&Vs[ni*16+l16][32+quad*8];
      oacc[ni] = __builtin_amdgcn_mfma_f32_16x16x32_bf16(a0, b0, oacc[ni],0,0,0);
      oacc[ni] = __builtin_amdgcn_mfma_f32_16x16x32_bf16(a1, b1, oacc[ni],0,0,0);
    }
  }

  // reduce l across the 16 lanes of each quad-row group
  #pragma unroll
  for (int off=1; off<16; off<<=1) {
    #pragma unroll
    for (int r=0; r<4; ++r) lrow[r] += __shfl_xor(lrow[r], off);
  }
  #pragma unroll
  for (int r=0; r<4; ++r) {
    float inv = 1.f / lrow[r];
    int tq = q0 + wm + quad*4 + r;
    __hip_bfloat16* yr = Yb + ((size_t)(b*TSEQ + tq))*N_EMBD + h*HD;
    #pragma unroll
    for (int ni=0; ni<4; ++ni)
      yr[ni*16 + l16] = __float2bfloat16(oacc[ni][r] * inv);
  }
}

extern "C" void kernel_launch(void* const* d_in, const int* in_sizes, int n_in,
                              void* d_out, int out_size, void* d_ws, size_t ws_size,
                              hipStream_t stream) {
  const float* x  = (const float*)d_in[0];
  const float* Wq = (const float*)d_in[1];
  const float* Wk = (const float*)d_in[2];
  const float* Wv = (const float*)d_in[3];
  const float* Wp = (const float*)d_in[4];
  const float* bp = (const float*)d_in[5];

  char* w = (char*)d_ws;
  __hip_bfloat16* xb    = (__hip_bfloat16*)w;  w += (size_t)M_TOT*N_EMBD*2;   // 16 MB
  __hip_bfloat16* wqkvt = (__hip_bfloat16*)w;  w += (size_t)3*N_EMBD*N_EMBD*2;// 6 MB
  __hip_bfloat16* wpt   = (__hip_bfloat16*)w;  w += (size_t)N_EMBD*N_EMBD*2;  // 2 MB
  __hip_bfloat16* Qb    = (__hip_bfloat16*)w;  w += (size_t)M_TOT*N_EMBD*2;   // 16 MB
  __hip_bfloat16* Kb    = (__hip_bfloat16*)w;  w += (size_t)M_TOT*N_EMBD*2;   // 16 MB
  __hip_bfloat16* Vt    = (__hip_bfloat16*)w;  w += (size_t)M_TOT*N_EMBD*2;   // 16 MB [B,H,d,T]
  __hip_bfloat16* Yb    = (__hip_bfloat16*)w;                                  // 16 MB (88 MB total)

  xcast_kernel<<<dim3(M_TOT*N_EMBD/1024), dim3(256), 0, stream>>>(x, xb);
  wcast_kernel<<<dim3(32,32,4), dim3(32,8), 0, stream>>>(Wq,Wk,Wv,Wp,wqkvt,wpt);
  gemm_kernel<<<dim3(48,128), dim3(256), 0, stream>>>(xb, wqkvt, Qb,Kb,Vt, nullptr, nullptr, 0);
  attn_kernel<<<dim3(TSEQ/64,N_HEADS,BATCH), dim3(256), 0, stream>>>(Qb,Kb,Vt,Yb);
  gemm_kernel<<<dim3(16,128), dim3(256), 0, stream>>>(Yb, wpt, nullptr,nullptr,nullptr,
                                                      (float*)d_out, bp, 1);
}

// Round 4
// 312.849 us; speedup vs baseline: 7.6391x; 1.2395x over previous
//
#include <hip/hip_runtime.h>
#include <hip/hip_bf16.h>

#define N_EMBD 1024
#define N_HEADS 16
#define HD 64
#define TSEQ 2048
#define BATCH 4
#define M_TOT (BATCH*TSEQ)   // 8192

typedef short s16x8 __attribute__((ext_vector_type(8)));
typedef float f32x4 __attribute__((ext_vector_type(4)));

__device__ __forceinline__ void glds16(const void* g, void* l) {
  __builtin_amdgcn_global_load_lds((const __attribute__((address_space(1))) void*)g,
                                   (__attribute__((address_space(3))) void*)l, 16, 0, 0);
}

// ---- cast x fp32 -> bf16, 4 elems/thread ----
__global__ __launch_bounds__(256) void xcast_kernel(const float* __restrict__ x,
                                                    __hip_bfloat16* __restrict__ xb) {
  int i = blockIdx.x * 256 + threadIdx.x;
  float4 f = ((const float4*)x)[i];
  __hip_bfloat162 p0, p1;
  p0.x = __float2bfloat16(f.x); p0.y = __float2bfloat16(f.y);
  p1.x = __float2bfloat16(f.z); p1.y = __float2bfloat16(f.w);
  ((__hip_bfloat162*)xb)[2*i]   = p0;
  ((__hip_bfloat162*)xb)[2*i+1] = p1;
}

// ---- transpose + cast weights: out[n][c] = in[c][n], bf16 ----
__global__ void wcast_kernel(const float* __restrict__ Wq, const float* __restrict__ Wk,
                             const float* __restrict__ Wv, const float* __restrict__ Wp,
                             __hip_bfloat16* __restrict__ wqkvt, __hip_bfloat16* __restrict__ wpt) {
  __shared__ float tile[32][33];
  int z = blockIdx.z;
  const float* in = (z==0)?Wq:(z==1)?Wk:(z==2)?Wv:Wp;
  __hip_bfloat16* out = (z<3) ? (wqkvt + (size_t)z*N_EMBD*N_EMBD) : wpt;
  int tx = threadIdx.x, ty = threadIdx.y;
  int x  = blockIdx.x*32 + tx;
  int y0 = blockIdx.y*32;
  #pragma unroll
  for (int j=0;j<4;++j) tile[ty + j*8][tx] = in[(size_t)(y0+ty+j*8)*N_EMBD + x];
  __syncthreads();
  int xo  = y0 + tx;
  int yo0 = blockIdx.x*32;
  #pragma unroll
  for (int j=0;j<4;++j)
    out[(size_t)(yo0+ty+j*8)*N_EMBD + xo] = __float2bfloat16(tile[tx][ty+j*8]);
}

// ---- bf16 MFMA GEMM, m97-style: 128x128 tile, BK=64, glds16 staging ----
// LDS layout is XOR-swizzled on the GLOBAL fetch side: physical 16B-group g
// holds logical group g^(row&7)  (glds LDS side must stay linear lane*16).
// mode 0: N=3072 (QKV). Q,K scatter [B,H,T,d]; V stored TRANSPOSED [B,H,d,T].
// mode 1: N=1024 (proj), out fp32 = acc + bias.
__global__ __launch_bounds__(256) void gemm_kernel(
    const __hip_bfloat16* __restrict__ A,   // [M][1024] bf16
    const __hip_bfloat16* __restrict__ Bt,  // [N][1024] bf16 (transposed weight)
    __hip_bfloat16* __restrict__ Qb, __hip_bfloat16* __restrict__ Kb,
    __hip_bfloat16* __restrict__ Vt,        // [B,H,d,T]
    float* __restrict__ out, const float* __restrict__ bias, int mode) {
  __shared__ __align__(16) char smem[32768];
  __hip_bfloat16* Alin = (__hip_bfloat16*)smem;            // 128x64
  __hip_bfloat16* Blin = (__hip_bfloat16*)(smem + 16384);  // 128x64
  int tid = threadIdx.x;
  int m0 = blockIdx.y*128, n0 = blockIdx.x*128;
  int w = tid>>6, lane = tid&63, l16 = lane&15, quad = lane>>4;
  int wr = w>>1, wc = w&1;
  int xg = l16 & 7;
  int off0 = ((quad    ) ^ xg)*8;   // physical col offset for logical k-chunk 0
  int off1 = ((quad + 4) ^ xg)*8;   // logical group c*4+quad, c=1
  f32x4 acc[4][4];
  #pragma unroll
  for (int mi=0;mi<4;++mi)
    #pragma unroll
    for (int ni=0;ni<4;++ni) acc[mi][ni] = (f32x4){0.f,0.f,0.f,0.f};

  for (int k0=0; k0<N_EMBD; k0+=64) {
    __syncthreads();   // prev frag reads done before restaging
    #pragma unroll
    for (int rd=0; rd<4; ++rd) {
      int slot = rd*256 + tid;
      int row  = slot>>3;
      int gc8  = ((tid&7) ^ (row&7))*8;
      glds16(A  + (size_t)(m0+row)*N_EMBD + k0 + gc8, Alin + slot*8);
      glds16(Bt + (size_t)(n0+row)*N_EMBD + k0 + gc8, Blin + slot*8);
    }
    __syncthreads();   // drain vmcnt
    #pragma unroll
    for (int c=0;c<2;++c) {
      int off = c ? off1 : off0;
      s16x8 af[4], bfr[4];
      #pragma unroll
      for (int mi=0;mi<4;++mi)
        af[mi] = *(const s16x8*)(Alin + (wr*64+mi*16+l16)*64 + off);
      #pragma unroll
      for (int ni=0;ni<4;++ni)
        bfr[ni] = *(const s16x8*)(Blin + (wc*64+ni*16+l16)*64 + off);
      #pragma unroll
      for (int mi=0;mi<4;++mi)
        #pragma unroll
        for (int ni=0;ni<4;++ni)
          acc[mi][ni] = __builtin_amdgcn_mfma_f32_16x16x32_bf16(af[mi], bfr[ni], acc[mi][ni],0,0,0);
    }
  }

  if (mode == 0) {
    int which = n0 >> 10;
    int bb = m0 >> 11, t0 = m0 & 2047;
    if (which < 2) {
      __hip_bfloat16* outp = (which==0)?Qb:Kb;
      #pragma unroll
      for (int mi=0;mi<4;++mi) {
        #pragma unroll
        for (int ni=0;ni<4;++ni) {
          int ncol = (n0 & 1023) + wc*64 + ni*16 + l16;
          int hh = ncol>>6, dd = ncol&63;
          #pragma unroll
          for (int r=0;r<4;++r) {
            int t = t0 + wr*64 + mi*16 + quad*4 + r;
            outp[((size_t)(bb*N_HEADS + hh)*TSEQ + t)*HD + dd] = __float2bfloat16(acc[mi][ni][r]);
          }
        }
      }
    } else {
      // V: transpose 128x128 tile (2 heads) in LDS, store [B,H,d,T]
      int hh0 = (n0 & 1023) >> 6;
      __hip_bfloat16 (*Ts)[136] = (__hip_bfloat16(*)[136])smem;  // 64x136x2=17408
      #pragma unroll
      for (int p=0;p<2;++p) {
        __syncthreads();   // Ts region free (prev frag reads / prev pass stores done)
        if (wc == p) {
          #pragma unroll
          for (int mi=0;mi<4;++mi)
            #pragma unroll
            for (int ni=0;ni<4;++ni) {
              int dd = ni*16 + l16;
              #pragma unroll
              for (int r=0;r<4;++r)
                Ts[dd][wr*64 + mi*16 + quad*4 + r] = __float2bfloat16(acc[mi][ni][r]);
            }
        }
        __syncthreads();
        int dd = tid>>2, tc = (tid&3)*32;
        __hip_bfloat16* dst = Vt + ((size_t)(bb*N_HEADS + hh0 + p)*HD + dd)*TSEQ + t0 + tc;
        #pragma unroll
        for (int c4=0;c4<4;++c4)
          *(uint4*)(dst + c4*8) = *(const uint4*)&Ts[dd][tc + c4*8];
      }
    }
  } else {
    #pragma unroll
    for (int mi=0;mi<4;++mi) {
      #pragma unroll
      for (int ni=0;ni<4;++ni) {
        int col = n0 + wc*64 + ni*16 + l16;
        float bs = bias[col];
        #pragma unroll
        for (int r=0;r<4;++r) {
          int m = m0 + wr*64 + mi*16 + quad*4 + r;
          out[(size_t)m*N_EMBD + col] = acc[mi][ni][r] + bs;
        }
      }
    }
  }
}

// ---- MFMA causal flash attention, 128 queries/block, 32 q/wave ----
// K/V staged via glds16 (XOR-swizzled global fetch). P round-trips through
// Ps with row stride 68 bf16 (136B): rows hold 64 data + 4 pad. P-writes hit
// banks (quad*8 + l16/2)%32 -> 2-way only (free); frag reads are 2x 8B loads
// (every offset is a multiple of 8B).  [R3 bug: stride 36 < 64 data columns
// made rows alias -> absmax 12.4]
#define PST 68
__global__ __launch_bounds__(256) void attn_kernel(
    const __hip_bfloat16* __restrict__ Qb, const __hip_bfloat16* __restrict__ Kb,
    const __hip_bfloat16* __restrict__ Vt, __hip_bfloat16* __restrict__ Yb) {
  __shared__ __align__(16) __hip_bfloat16 Ks[64][64];    // [key][d] swizzled
  __shared__ __align__(16) __hip_bfloat16 Vs[64][64];    // [d][key] swizzled
  __shared__ __align__(16) __hip_bfloat16 Ps[128][PST];  // [q][key]
  int tid = threadIdx.x;
  int qb = blockIdx.x, h = blockIdx.y, b = blockIdx.z;
  int q0 = qb*128;
  size_t bhT  = (size_t)(b*N_HEADS + h)*TSEQ;
  size_t bhHD = (size_t)(b*N_HEADS + h)*HD;
  int lane = tid&63, w = tid>>6, l16 = lane&15, quad = lane>>4;
  int wq = w*32;                       // wave's query band
  int xg = l16 & 7;
  int off0 = ((quad    ) ^ xg)*8;
  int off1 = ((quad + 4) ^ xg)*8;

  // Q fragments (A-layout) for 2 q-tiles x 2 k-chunks
  s16x8 qf[2][2];
  #pragma unroll
  for (int mi=0;mi<2;++mi) {
    const __hip_bfloat16* qrow = Qb + (bhT + q0 + wq + mi*16 + l16)*HD;
    qf[mi][0] = *(const s16x8*)(qrow + quad*8);
    qf[mi][1] = *(const s16x8*)(qrow + 32 + quad*8);
  }

  f32x4 z4 = {0.f,0.f,0.f,0.f};
  f32x4 oacc[4][2];
  #pragma unroll
  for (int ni=0;ni<4;++ni) { oacc[ni][0]=z4; oacc[ni][1]=z4; }
  float lrow[2][4] = {{0.f,0.f,0.f,0.f},{0.f,0.f,0.f,0.f}};

  int ntiles = 2*qb + 2;
  for (int t=0; t<ntiles; ++t) {
    int k0 = t*64;
    __syncthreads();   // prev tile frag reads done before restaging
    #pragma unroll
    for (int rd=0; rd<2; ++rd) {
      int slot = rd*256 + tid;
      int row  = slot>>3;
      int gc8  = ((tid&7) ^ (row&7))*8;
      glds16(Kb + (bhT + k0 + row)*HD + gc8,       &Ks[0][0] + slot*8);
      glds16(Vt + (bhHD + row)*TSEQ + k0 + gc8,    &Vs[0][0] + slot*8);
    }
    __syncthreads();   // drain vmcnt

    // S = Q K^T : 32q x 64key per wave
    f32x4 sacc[4][2];
    #pragma unroll
    for (int ni=0; ni<4; ++ni) {
      s16x8 kb0 = *(const s16x8*)(&Ks[0][0] + (ni*16+l16)*64 + off0);
      s16x8 kb1 = *(const s16x8*)(&Ks[0][0] + (ni*16+l16)*64 + off1);
      #pragma unroll
      for (int mi=0; mi<2; ++mi) {
        f32x4 s = z4;
        s = __builtin_amdgcn_mfma_f32_16x16x32_bf16(qf[mi][0], kb0, s,0,0,0);
        s = __builtin_amdgcn_mfma_f32_16x16x32_bf16(qf[mi][1], kb1, s,0,0,0);
        sacc[ni][mi] = s;
      }
    }

    // mask + exp; accumulate l; P -> LDS (own band; same-wave lgkmcnt ordering)
    #pragma unroll
    for (int ni=0; ni<4; ++ni) {
      int kcol = k0 + ni*16 + l16;
      #pragma unroll
      for (int mi=0; mi<2; ++mi) {
        int qrb = q0 + wq + mi*16 + quad*4;
        #pragma unroll
        for (int r=0; r<4; ++r) {
          float p = (qrb + r >= kcol) ? __expf(sacc[ni][mi][r]*0.125f) : 0.f;
          lrow[mi][r] += p;
          Ps[wq + mi*16 + quad*4 + r][ni*16 + l16] = __float2bfloat16(p);
        }
      }
    }

    // O += P V
    union U8 { s16x8 v; uint2 u[2]; };
    U8 aP[2][2];
    #pragma unroll
    for (int mi=0; mi<2; ++mi)
      #pragma unroll
      for (int c=0; c<2; ++c) {
        const __hip_bfloat16* pr = &Ps[wq + mi*16 + l16][c*32 + quad*8];
        aP[mi][c].u[0] = *(const uint2*)pr;
        aP[mi][c].u[1] = *(const uint2*)(pr + 4);
      }
    #pragma unroll
    for (int ni=0; ni<4; ++ni) {
      s16x8 vb0 = *(const s16x8*)(&Vs[0][0] + (ni*16+l16)*64 + off0);
      s16x8 vb1 = *(const s16x8*)(&Vs[0][0] + (ni*16+l16)*64 + off1);
      #pragma unroll
      for (int mi=0; mi<2; ++mi) {
        oacc[ni][mi] = __builtin_amdgcn_mfma_f32_16x16x32_bf16(aP[mi][0].v, vb0, oacc[ni][mi],0,0,0);
        oacc[ni][mi] = __builtin_amdgcn_mfma_f32_16x16x32_bf16(aP[mi][1].v, vb1, oacc[ni][mi],0,0,0);
      }
    }
  }

  // reduce l across the 16 lanes of each quad-row group
  #pragma unroll
  for (int off=1; off<16; off<<=1)
    #pragma unroll
    for (int mi=0; mi<2; ++mi)
      #pragma unroll
      for (int r=0; r<4; ++r) lrow[mi][r] += __shfl_xor(lrow[mi][r], off);

  #pragma unroll
  for (int mi=0; mi<2; ++mi)
    #pragma unroll
    for (int r=0; r<4; ++r) {
      float inv = 1.f / lrow[mi][r];
      int tq = q0 + wq + mi*16 + quad*4 + r;
      __hip_bfloat16* yr = Yb + ((size_t)(b*TSEQ + tq))*N_EMBD + h*HD;
      #pragma unroll
      for (int ni=0; ni<4; ++ni)
        yr[ni*16 + l16] = __float2bfloat16(oacc[ni][mi][r] * inv);
    }
}

extern "C" void kernel_launch(void* const* d_in, const int* in_sizes, int n_in,
                              void* d_out, int out_size, void* d_ws, size_t ws_size,
                              hipStream_t stream) {
  const float* x  = (const float*)d_in[0];
  const float* Wq = (const float*)d_in[1];
  const float* Wk = (const float*)d_in[2];
  const float* Wv = (const float*)d_in[3];
  const float* Wp = (const float*)d_in[4];
  const float* bp = (const float*)d_in[5];

  char* w = (char*)d_ws;
  __hip_bfloat16* xb    = (__hip_bfloat16*)w;  w += (size_t)M_TOT*N_EMBD*2;   // 16 MB
  __hip_bfloat16* wqkvt = (__hip_bfloat16*)w;  w += (size_t)3*N_EMBD*N_EMBD*2;// 6 MB
  __hip_bfloat16* wpt   = (__hip_bfloat16*)w;  w += (size_t)N_EMBD*N_EMBD*2;  // 2 MB
  __hip_bfloat16* Qb    = (__hip_bfloat16*)w;  w += (size_t)M_TOT*N_EMBD*2;   // 16 MB
  __hip_bfloat16* Kb    = (__hip_bfloat16*)w;  w += (size_t)M_TOT*N_EMBD*2;   // 16 MB
  __hip_bfloat16* Vt    = (__hip_bfloat16*)w;  w += (size_t)M_TOT*N_EMBD*2;   // 16 MB [B,H,d,T]
  __hip_bfloat16* Yb    = (__hip_bfloat16*)w;                                  // 16 MB (88 MB total)

  xcast_kernel<<<dim3(M_TOT*N_EMBD/1024), dim3(256), 0, stream>>>(x, xb);
  wcast_kernel<<<dim3(32,32,4), dim3(32,8), 0, stream>>>(Wq,Wk,Wv,Wp,wqkvt,wpt);
  gemm_kernel<<<dim3(24,64), dim3(256), 0, stream>>>(xb, wqkvt, Qb,Kb,Vt, nullptr, nullptr, 0);
  attn_kernel<<<dim3(TSEQ/128,N_HEADS,BATCH), dim3(256), 0, stream>>>(Qb,Kb,Vt,Yb);
  gemm_kernel<<<dim3(8,64), dim3(256), 0, stream>>>(Yb, wpt, nullptr,nullptr,nullptr,
                                                    (float*)d_out, bp, 1);
}